// Round 1
// baseline (511.454 us; speedup 1.0000x reference)
//
#include <hip/hip_runtime.h>

// MMEAttn decode: B=64, QT=1, KVT=256, M=32, H=128, fp32 in/out.
// out[b,m,0,h] = softmax_t( q[b,0,m,:]·k[b,t,m,:] ) · v[:,m,h]
// Memory-bound: K+V = 537 MB must stream once. 1 block per (b,m).

constexpr int KVT = 256;
constexpr int M   = 32;
constexpr int H   = 128;
constexpr int MH  = M * H;   // 4096

__global__ __launch_bounds__(256) void mme_attn_kernel(
    const float* __restrict__ q,
    const float* __restrict__ k,
    const float* __restrict__ v,
    float* __restrict__ out)
{
    __shared__ float  q_s[H];        // 512 B, broadcast reads
    __shared__ float  sc[KVT];       // 1 KB, softmax probs
    __shared__ float  red[8];        // wave partials (4 max, 4 sum)
    __shared__ float4 o4[256];       // 4 KB, PV segment partials

    const int bm  = blockIdx.x;      // 0..2047 = b*32 + m
    const int b   = bm >> 5;
    const int m   = bm & 31;
    const int tid = threadIdx.x;

    const size_t kbase = (size_t)b * KVT * MH + (size_t)m * H;

    // stage q[b,0,m,:] into LDS
    if (tid < H) q_s[tid] = q[(size_t)b * MH + (size_t)m * H + tid];
    __syncthreads();

    // ---- Phase 1: score[tid] = dot(q, k_tid) over H=128 ----
    float s;
    {
        const float4* kp = (const float4*)(k + kbase + (size_t)tid * MH);
        const float4* qp = (const float4*)q_s;
        float acc = 0.f;
#pragma unroll
        for (int i = 0; i < H / 4; ++i) {
            float4 kk = kp[i];      // per-lane contiguous 512 B row
            float4 qq = qp[i];      // LDS broadcast
            acc += kk.x * qq.x + kk.y * qq.y + kk.z * qq.z + kk.w * qq.w;
        }
        s = acc;
    }

    // ---- softmax over 256 scores (no 1/sqrt(H) scaling, per reference) ----
    const int lane = tid & 63;
    const int wv   = tid >> 6;

    float mx = s;
#pragma unroll
    for (int off = 32; off > 0; off >>= 1)
        mx = fmaxf(mx, __shfl_xor(mx, off));
    if (lane == 0) red[wv] = mx;
    __syncthreads();
    mx = fmaxf(fmaxf(red[0], red[1]), fmaxf(red[2], red[3]));

    float p = __expf(s - mx);
    float sm = p;
#pragma unroll
    for (int off = 32; off > 0; off >>= 1)
        sm += __shfl_xor(sm, off);
    if (lane == 0) red[4 + wv] = sm;
    __syncthreads();
    sm = (red[4] + red[5]) + (red[6] + red[7]);

    sc[tid] = p * __frcp_rn(sm);
    __syncthreads();

    // ---- Phase 2: out[h] = sum_t p[t] * v[t][h], float4 per thread ----
    const int c4  = tid & 31;   // which float4 column (h = c4*4..c4*4+3)
    const int seg = tid >> 5;   // 0..7, each seg covers 32 KV rows

    float4 acc4 = {0.f, 0.f, 0.f, 0.f};
    const float* vb = v + kbase + (size_t)c4 * 4;
#pragma unroll 4
    for (int t = seg * 32; t < seg * 32 + 32; ++t) {
        float pt  = sc[t];                                  // LDS broadcast
        float4 vv = *(const float4*)(vb + (size_t)t * MH);  // coalesced 16B/lane
        acc4.x += pt * vv.x;
        acc4.y += pt * vv.y;
        acc4.z += pt * vv.z;
        acc4.w += pt * vv.w;
    }
    o4[tid] = acc4;
    __syncthreads();

    // combine 8 segment partials, write out[b,m,0,:]
    if (tid < 32) {
        float4 r = o4[tid];
#pragma unroll
        for (int sgi = 1; sgi < 8; ++sgi) {
            float4 t4 = o4[sgi * 32 + tid];
            r.x += t4.x; r.y += t4.y; r.z += t4.z; r.w += t4.w;
        }
        ((float4*)(out + (size_t)bm * H))[tid] = r;
    }
}

extern "C" void kernel_launch(void* const* d_in, const int* in_sizes, int n_in,
                              void* d_out, int out_size, void* d_ws, size_t ws_size,
                              hipStream_t stream) {
    const float* q = (const float*)d_in[0];
    const float* k = (const float*)d_in[1];
    const float* v = (const float*)d_in[2];
    float* out = (float*)d_out;

    // grid: one block per (b, m) head pair = 64*32 = 2048 blocks
    mme_attn_kernel<<<2048, 256, 0, stream>>>(q, k, v, out);
}